// Round 4
// baseline (512.152 us; speedup 1.0000x reference)
//
#include <hip/hip_runtime.h>
#include <hip/hip_bf16.h>
#include <math.h>

typedef unsigned short u16;
typedef unsigned int u32;

typedef __bf16 bf16x8 __attribute__((ext_vector_type(8)));
typedef float f32x4 __attribute__((ext_vector_type(4)));

union U8 { uint4 u; u16 s[8]; };

__device__ __forceinline__ float b2f(u16 x) {
    u32 y = ((u32)x) << 16;
    return __builtin_bit_cast(float, y);
}
__device__ __forceinline__ u16 f2b(float f) {
    u32 x = __builtin_bit_cast(u32, f);
    u32 r = x + 0x7fffu + ((x >> 16) & 1u);
    return (u16)(r >> 16);
}
// pack 8 fp32 -> 8 bf16 (one uint4)
__device__ __forceinline__ uint4 cvt8(float4 a, float4 b) {
    U8 o;
    o.s[0] = f2b(a.x); o.s[1] = f2b(a.y); o.s[2] = f2b(a.z); o.s[3] = f2b(a.w);
    o.s[4] = f2b(b.x); o.s[5] = f2b(b.y); o.s[6] = f2b(b.z); o.s[7] = f2b(b.w);
    return o.u;
}

// ---------------- small kernels ----------------

__global__ void __launch_bounds__(64) zero_ss(float* ss) {
    if (threadIdx.x < 2) ss[threadIdx.x] = 0.f;
}

// sum of squares of Wv (y=0) / Wq (y=1), each 3072*1024 fp32
__global__ void __launch_bounds__(256) sumsq_k(const float* __restrict__ Wv,
                                               const float* __restrict__ Wq,
                                               float* __restrict__ ss, int n) {
    const float* W = (blockIdx.y == 0) ? Wv : Wq;
    float acc = 0.f;
    size_t stride = (size_t)gridDim.x * 256 * 8;
    for (size_t i = ((size_t)blockIdx.x * 256 + threadIdx.x) * 8; i < (size_t)n; i += stride) {
        float4 a = *(const float4*)(W + i);
        float4 b = *(const float4*)(W + i + 4);
        acc += a.x * a.x + a.y * a.y + a.z * a.z + a.w * a.w;
        acc += b.x * b.x + b.y * b.y + b.z * b.z + b.w * b.w;
    }
#pragma unroll
    for (int o = 32; o > 0; o >>= 1) acc += __shfl_down(acc, o, 64);
    __shared__ float red[4];
    int lane = threadIdx.x & 63, wv = threadIdx.x >> 6;
    if (lane == 0) red[wv] = acc;
    __syncthreads();
    if (threadIdx.x == 0) atomicAdd(&ss[blockIdx.y], red[0] + red[1] + red[2] + red[3]);
}

// Wv fp32 (3072 x 1024) -> WvT bf16 (1024 x 3072)
__global__ void __launch_bounds__(256) transpose_k(const float* __restrict__ in, u16* __restrict__ out) {
    __shared__ u16 t[32][33];
    int x = blockIdx.x * 32 + threadIdx.x;  // col of in (0..1023)
    int y0 = blockIdx.y * 32;               // row base of in (0..3071)
#pragma unroll
    for (int j = threadIdx.y; j < 32; j += 8)
        t[j][threadIdx.x] = f2b(in[(size_t)(y0 + j) * 1024 + x]);
    __syncthreads();
    int x2 = y0 + threadIdx.x;              // col of out
    int y2 = blockIdx.x * 32;               // row base of out
#pragma unroll
    for (int j = threadIdx.y; j < 32; j += 8)
        out[(size_t)(y2 + j) * 3072 + x2] = t[threadIdx.x][j];
}

// cb[b*1024 + h*128 + d] = sum_k bv[k]*hm[h,k]*q_[b*128+d, k]   (fp32 acc)
__global__ void __launch_bounds__(256) const_k(const u16* __restrict__ qbuf,
                                               const float* __restrict__ bv,
                                               const float* __restrict__ hm,
                                               float* __restrict__ cb) {
    int idx = blockIdx.x * 256 + threadIdx.x;  // 0..16383
    int b = idx >> 10, hd = idx & 1023, h = hd >> 7, d = hd & 127;
    const u16* qr = qbuf + ((size_t)b * 128 + d) * 3072;
    const float* hr = hm + (size_t)h * 3072;
    float acc = 0.f;
    for (int k = 0; k < 3072; k += 8) {
        U8 uq; uq.u = *(const uint4*)(qr + k);
        float4 h0 = *(const float4*)(hr + k);
        float4 h1 = *(const float4*)(hr + k + 4);
        float4 b0 = *(const float4*)(bv + k);
        float4 b1 = *(const float4*)(bv + k + 4);
        acc += b2f(uq.s[0]) * h0.x * b0.x + b2f(uq.s[1]) * h0.y * b0.y +
               b2f(uq.s[2]) * h0.z * b0.z + b2f(uq.s[3]) * h0.w * b0.w +
               b2f(uq.s[4]) * h1.x * b1.x + b2f(uq.s[5]) * h1.y * b1.y +
               b2f(uq.s[6]) * h1.z * b1.z + b2f(uq.s[7]) * h1.w * b1.w;
    }
    cb[idx] = acc;
}

// ---------------- main BT-GEMM (register-prefetch, fp32->bf16 staging) ----------------
// C(M x N) = A(M x kdim) * Bt(N x kdim)^T, 128x128 tile, BK=32, 4 waves 2x2.
// EPI 0: A=q fp32, B=Wq fp32.     qbuf[r*3072+c] = bf16(acc*scale + bq[c])
// EPI 1: A=hm(fp32)*qbuf(bf16) on the fly, B=wvt bf16.  tbuf[bl*1M + r*1024 + c] = bf16(acc)
// EPI 2: A=v fp32, B=tbuf bf16.   out[((b*8+h)*1024+r)*128+d] = fp32(acc*scale + cb + hbias[h])
template <int EPI>
__global__ void __launch_bounds__(256)
gemm_bt(const void* __restrict__ Ap, const void* __restrict__ Bp, void* __restrict__ C,
        const u16* __restrict__ qbuf, const float* __restrict__ hm,
        const float* __restrict__ ss, int ss_idx, const float* __restrict__ g,
        const float* __restrict__ bias, const float* __restrict__ cb,
        const float* __restrict__ hbias, int kdim, size_t abatch, size_t bbatch, int b0) {
    constexpr int BK = 32;
    constexpr bool B_F32 = (EPI == 0);
    __shared__ __align__(16) u16 sA[128 * BK];
    __shared__ __align__(16) u16 sB[128 * BK];

    const int tid = threadIdx.x;
    const int lane = tid & 63, wv = tid >> 6;
    const int wm = (wv & 1) * 64, wn = (wv >> 1) * 64;
    const int lr = lane & 15, quad = lane >> 4;
    const int bl = blockIdx.z;
    const int b = b0 + bl;
    const int arow0 = blockIdx.y * 128;
    const int bcol0 = blockIdx.x * 128;

    // staging map: thread t covers LDS row r0 (and r0+64), cols [c0, c0+8)
    const int r0 = tid >> 2, c0 = (tid & 3) * 8;

    // ---- operand pointers ----
    const float* fA0 = nullptr; const float* fA1 = nullptr;   // fp32 A
    const u16* qA0 = nullptr;   const u16* qA1 = nullptr;     // bf16 q_ (EPI1)
    const float* pH = nullptr;                                // fp32 hm (EPI1)
    const float* fB0 = nullptr; const float* fB1 = nullptr;   // fp32 B
    const u16* uB0 = nullptr;   const u16* uB1 = nullptr;     // bf16 B

    if constexpr (EPI == 1) {
        qA0 = qbuf + ((size_t)b * 128 + r0) * 3072 + c0;
        qA1 = qA0 + (size_t)64 * 3072;
        pH = hm + (size_t)blockIdx.y * 3072 + c0;
    } else {
        const float* Ab = (const float*)Ap + (size_t)b * abatch;
        fA0 = Ab + (size_t)(arow0 + r0) * kdim + c0;
        fA1 = fA0 + (size_t)64 * kdim;
    }
    if constexpr (B_F32) {
        fB0 = (const float*)Bp + (size_t)(bcol0 + r0) * kdim + c0;
        fB1 = fB0 + (size_t)64 * kdim;
    } else {
        uB0 = (const u16*)Bp + (size_t)bl * bbatch + (size_t)(bcol0 + r0) * kdim + c0;
        uB1 = uB0 + (size_t)64 * kdim;
    }

    // ---- prefetch tile 0 ----
    float4 a0a, a0b, a1a, a1b, b0a, b0b, b1a, b1b, h0, h1;
    uint4 ua0 = {0,0,0,0}, ua1 = {0,0,0,0}, ub0 = {0,0,0,0}, ub1 = {0,0,0,0};
    if constexpr (EPI == 1) {
        ua0 = *(const uint4*)qA0; ua1 = *(const uint4*)qA1;
        h0 = *(const float4*)pH; h1 = *(const float4*)(pH + 4);
        qA0 += BK; qA1 += BK; pH += BK;
    } else {
        a0a = *(const float4*)fA0; a0b = *(const float4*)(fA0 + 4);
        a1a = *(const float4*)fA1; a1b = *(const float4*)(fA1 + 4);
        fA0 += BK; fA1 += BK;
    }
    if constexpr (B_F32) {
        b0a = *(const float4*)fB0; b0b = *(const float4*)(fB0 + 4);
        b1a = *(const float4*)fB1; b1b = *(const float4*)(fB1 + 4);
        fB0 += BK; fB1 += BK;
    } else {
        ub0 = *(const uint4*)uB0; ub1 = *(const uint4*)uB1;
        uB0 += BK; uB1 += BK;
    }

    f32x4 acc[4][4];
#pragma unroll
    for (int im = 0; im < 4; im++)
#pragma unroll
        for (int in = 0; in < 4; in++) acc[im][in] = (f32x4){0.f, 0.f, 0.f, 0.f};

    for (int kt = 0; kt < kdim; kt += BK) {
        __syncthreads();
        if constexpr (EPI == 1) {
            U8 q0, q1, o0, o1;
            q0.u = ua0; q1.u = ua1;
            float hf[8] = {h0.x, h0.y, h0.z, h0.w, h1.x, h1.y, h1.z, h1.w};
#pragma unroll
            for (int j = 0; j < 8; j++) {
                o0.s[j] = f2b(hf[j] * b2f(q0.s[j]));
                o1.s[j] = f2b(hf[j] * b2f(q1.s[j]));
            }
            *(uint4*)(sA + (size_t)tid * 8) = o0.u;
            *(uint4*)(sA + 2048 + (size_t)tid * 8) = o1.u;
        } else {
            *(uint4*)(sA + (size_t)tid * 8) = cvt8(a0a, a0b);
            *(uint4*)(sA + 2048 + (size_t)tid * 8) = cvt8(a1a, a1b);
        }
        if constexpr (B_F32) {
            *(uint4*)(sB + (size_t)tid * 8) = cvt8(b0a, b0b);
            *(uint4*)(sB + 2048 + (size_t)tid * 8) = cvt8(b1a, b1b);
        } else {
            *(uint4*)(sB + (size_t)tid * 8) = ub0;
            *(uint4*)(sB + 2048 + (size_t)tid * 8) = ub1;
        }
        __syncthreads();

        // prefetch next tile (overlaps with MFMA below)
        if (kt + BK < kdim) {
            if constexpr (EPI == 1) {
                ua0 = *(const uint4*)qA0; ua1 = *(const uint4*)qA1;
                h0 = *(const float4*)pH; h1 = *(const float4*)(pH + 4);
                qA0 += BK; qA1 += BK; pH += BK;
            } else {
                a0a = *(const float4*)fA0; a0b = *(const float4*)(fA0 + 4);
                a1a = *(const float4*)fA1; a1b = *(const float4*)(fA1 + 4);
                fA0 += BK; fA1 += BK;
            }
            if constexpr (B_F32) {
                b0a = *(const float4*)fB0; b0b = *(const float4*)(fB0 + 4);
                b1a = *(const float4*)fB1; b1b = *(const float4*)(fB1 + 4);
                fB0 += BK; fB1 += BK;
            } else {
                ub0 = *(const uint4*)uB0; ub1 = *(const uint4*)uB1;
                uB0 += BK; uB1 += BK;
            }
        }

        bf16x8 af[4], bfr[4];
#pragma unroll
        for (int im = 0; im < 4; im++)
            af[im] = *(const bf16x8*)(sA + (wm + im * 16 + lr) * BK + quad * 8);
#pragma unroll
        for (int in = 0; in < 4; in++)
            bfr[in] = *(const bf16x8*)(sB + (wn + in * 16 + lr) * BK + quad * 8);
#pragma unroll
        for (int im = 0; im < 4; im++)
#pragma unroll
            for (int in = 0; in < 4; in++)
                acc[im][in] = __builtin_amdgcn_mfma_f32_16x16x32_bf16(af[im], bfr[in], acc[im][in], 0, 0, 0);
    }

    float scale = 1.f;
    if constexpr (EPI == 0 || EPI == 2) scale = g[0] / sqrtf(ss[ss_idx]);

#pragma unroll
    for (int im = 0; im < 4; im++) {
#pragma unroll
        for (int in = 0; in < 4; in++) {
#pragma unroll
            for (int reg = 0; reg < 4; reg++) {
                int gr = arow0 + wm + im * 16 + quad * 4 + reg;  // row (M)
                int gc = bcol0 + wn + in * 16 + lr;              // col (N)
                float val = acc[im][in][reg];
                if constexpr (EPI == 0) {
                    ((u16*)C)[(size_t)gr * 3072 + gc] = f2b(val * scale + bias[gc]);
                } else if constexpr (EPI == 1) {
                    ((u16*)C)[(size_t)bl * 1048576 + (size_t)gr * 1024 + gc] = f2b(val);
                } else {
                    int h = gc >> 7, d = gc & 127;
                    float o = val * scale + cb[(size_t)b * 1024 + gc] + hbias[h];
                    ((float*)C)[(((size_t)b * 8 + h) * 1024 + gr) * 128 + d] = o;
                }
            }
        }
    }
}

// ---------------- launch ----------------

extern "C" void kernel_launch(void* const* d_in, const int* in_sizes, int n_in,
                              void* d_out, int out_size, void* d_ws, size_t ws_size,
                              hipStream_t stream) {
    (void)in_sizes; (void)n_in; (void)out_size;
    const float* v  = (const float*)d_in[0];   // (16,1024,1024) fp32
    const float* q  = (const float*)d_in[1];   // (16,128,1024)  fp32
    const float* Wv = (const float*)d_in[2];   // (3072,1024)    fp32
    const float* gv = (const float*)d_in[3];
    const float* bv = (const float*)d_in[4];   // (3072)
    const float* Wq = (const float*)d_in[5];   // (3072,1024)
    const float* gq = (const float*)d_in[6];
    const float* bq = (const float*)d_in[7];   // (3072)
    const float* hm = (const float*)d_in[8];   // (8,3072)
    const float* hb = (const float*)d_in[9];   // (8)
    float* out = (float*)d_out;                // fp32 output (16,8,1024,128)

    char* ws = (char*)d_ws;
    float* ss   = (float*)ws;                                     // 2 floats
    float* cb   = (float*)(ws + 256);                             // 16384 floats
    u16*   qbuf = (u16*)(ws + 256 + 65536);                       // 2048*3072 bf16 = 12 MB
    u16*   wvt  = (u16*)(ws + 256 + 65536 + 12582912);            // 1024*3072 bf16 = 6 MB
    u16*   tbuf = (u16*)(ws + 256 + 65536 + 12582912 + 6291456);  // chunk*1024*1024 bf16
    const size_t fixed = 256 + 65536 + 12582912 + 6291456;        // 18,940,160 B

    // adaptive chunking of the T buffer (2 MB per batch) to fit ws_size
    int chunk = 16;
    if (ws_size < fixed + (size_t)16 * 2097152) {
        size_t avail = (ws_size > fixed) ? (ws_size - fixed) : 0;
        chunk = (int)(avail / 2097152);
        if (chunk < 1) chunk = 1;
        if (chunk > 16) chunk = 16;
    }

    zero_ss<<<1, 64, 0, stream>>>(ss);
    sumsq_k<<<dim3(256, 2), 256, 0, stream>>>(Wv, Wq, ss, 3072 * 1024);
    transpose_k<<<dim3(32, 96), dim3(32, 8), 0, stream>>>(Wv, wvt);

    // q_ = q * wn(Wq)^T + bq   (2048 x 3072), inputs fp32 -> bf16 staged
    gemm_bt<0><<<dim3(24, 16, 1), 256, 0, stream>>>(
        q, Wq, qbuf, nullptr, nullptr, ss, 1, gq, bq, nullptr, nullptr, 1024, 0, 0, 0);

    // cb[b,hd] = sum_k bv*hm*q_
    const_k<<<64, 256, 0, stream>>>(qbuf, bv, hm, cb);

    for (int b0 = 0; b0 < 16; b0 += chunk) {
        int nb = (16 - b0 < chunk) ? (16 - b0) : chunk;
        // T[b,hd,c] = sum_k (hm[h,k]*q_[b,d,k]) * Wv[k,c]   via WvT, A on-the-fly
        gemm_bt<1><<<dim3(8, 8, nb), 256, 0, stream>>>(
            nullptr, wvt, tbuf, qbuf, hm, ss, 0, nullptr, nullptr, nullptr, nullptr,
            3072, 0, 0, b0);
        // logits[b,h,n,d] = scale_v * sum_c v[b,n,c]*T[b,hd,c] + cb[b,hd] + hbias[h]
        gemm_bt<2><<<dim3(8, 8, nb), 256, 0, stream>>>(
            v, tbuf, out, nullptr, nullptr, ss, 0, gv, nullptr, cb, hb,
            1024, 1048576, 1048576, b0);
    }
}

// Round 5
// 503.682 us; speedup vs baseline: 1.0168x; 1.0168x over previous
//
#include <hip/hip_runtime.h>
#include <hip/hip_bf16.h>
#include <math.h>

typedef unsigned short u16;
typedef unsigned int u32;

typedef __bf16 bf16x8 __attribute__((ext_vector_type(8)));
typedef float f32x4 __attribute__((ext_vector_type(4)));

union U8 { uint4 u; u16 s[8]; };

__device__ __forceinline__ float b2f(u16 x) {
    u32 y = ((u32)x) << 16;
    return __builtin_bit_cast(float, y);
}
__device__ __forceinline__ u16 f2b(float f) {
    u32 x = __builtin_bit_cast(u32, f);
    u32 r = x + 0x7fffu + ((x >> 16) & 1u);
    return (u16)(r >> 16);
}
// pack 8 fp32 -> 8 bf16 (one uint4)
__device__ __forceinline__ uint4 cvt8(float4 a, float4 b) {
    U8 o;
    o.s[0] = f2b(a.x); o.s[1] = f2b(a.y); o.s[2] = f2b(a.z); o.s[3] = f2b(a.w);
    o.s[4] = f2b(b.x); o.s[5] = f2b(b.y); o.s[6] = f2b(b.z); o.s[7] = f2b(b.w);
    return o.u;
}

// async global->LDS, 16B per lane. LDS dest = wave-uniform base + lane*16.
typedef __attribute__((address_space(1))) u32 as1_u32;
typedef __attribute__((address_space(3))) u32 as3_u32;
__device__ __forceinline__ void gld16(const u16* g, u16* l) {
    __builtin_amdgcn_global_load_lds((as1_u32*)g, (as3_u32*)l, 16, 0, 0);
}

// ---------------- small kernels ----------------

__global__ void __launch_bounds__(64) zero_ss(float* ss) {
    if (threadIdx.x < 2) ss[threadIdx.x] = 0.f;
}

// sum of squares of Wv (y=0) / Wq (y=1), each 3072*1024 fp32
__global__ void __launch_bounds__(256) sumsq_k(const float* __restrict__ Wv,
                                               const float* __restrict__ Wq,
                                               float* __restrict__ ss, int n) {
    const float* W = (blockIdx.y == 0) ? Wv : Wq;
    float acc = 0.f;
    size_t stride = (size_t)gridDim.x * 256 * 8;
    for (size_t i = ((size_t)blockIdx.x * 256 + threadIdx.x) * 8; i < (size_t)n; i += stride) {
        float4 a = *(const float4*)(W + i);
        float4 b = *(const float4*)(W + i + 4);
        acc += a.x * a.x + a.y * a.y + a.z * a.z + a.w * a.w;
        acc += b.x * b.x + b.y * b.y + b.z * b.z + b.w * b.w;
    }
#pragma unroll
    for (int o = 32; o > 0; o >>= 1) acc += __shfl_down(acc, o, 64);
    __shared__ float red[4];
    int lane = threadIdx.x & 63, wv = threadIdx.x >> 6;
    if (lane == 0) red[wv] = acc;
    __syncthreads();
    if (threadIdx.x == 0) atomicAdd(&ss[blockIdx.y], red[0] + red[1] + red[2] + red[3]);
}

// wvh[h][c][k] = bf16(hm[h,k] * Wv[k,c])  -- fused transpose + 8-head scale
// Wv fp32 (3072 k x 1024 c), hm fp32 (8 x 3072), wvh bf16 (8 x 1024 x 3072)
__global__ void __launch_bounds__(256) twvh_k(const float* __restrict__ Wv,
                                              const float* __restrict__ hm,
                                              u16* __restrict__ wvh) {
    __shared__ float t[32][33];
    int cx0 = blockIdx.x * 32;   // c base
    int ky0 = blockIdx.y * 32;   // k base
    int tx = threadIdx.x, ty = threadIdx.y;
#pragma unroll
    for (int j = ty; j < 32; j += 8)
        t[j][tx] = Wv[(size_t)(ky0 + j) * 1024 + cx0 + tx];
    __syncthreads();
    int k = ky0 + tx;
    float hv[8];
#pragma unroll
    for (int h = 0; h < 8; h++) hv[h] = hm[(size_t)h * 3072 + k];
#pragma unroll
    for (int j = ty; j < 32; j += 8) {
        float w = t[tx][j];           // Wv[k][cx0+j]
        int c = cx0 + j;
#pragma unroll
        for (int h = 0; h < 8; h++)
            wvh[(size_t)h * 3145728 + (size_t)c * 3072 + k] = f2b(hv[h] * w);
    }
}

// vb[i] = bf16(v[i]), n elements
__global__ void __launch_bounds__(256) cvt_v(const float* __restrict__ v,
                                             u16* __restrict__ vb, int n) {
    size_t stride = (size_t)gridDim.x * 256 * 8;
    for (size_t i = ((size_t)blockIdx.x * 256 + threadIdx.x) * 8; i < (size_t)n; i += stride) {
        float4 a = *(const float4*)(v + i);
        float4 b = *(const float4*)(v + i + 4);
        *(uint4*)(vb + i) = cvt8(a, b);
    }
}

// cb[b*1024 + h*128 + d] = sum_k bv[k]*hm[h,k]*q_[b*128+d, k]   (fp32 acc)
__global__ void __launch_bounds__(256) const_k(const u16* __restrict__ qbuf,
                                               const float* __restrict__ bv,
                                               const float* __restrict__ hm,
                                               float* __restrict__ cb) {
    int idx = blockIdx.x * 256 + threadIdx.x;  // 0..16383
    int b = idx >> 10, hd = idx & 1023, h = hd >> 7, d = hd & 127;
    const u16* qr = qbuf + ((size_t)b * 128 + d) * 3072;
    const float* hr = hm + (size_t)h * 3072;
    float acc = 0.f;
    for (int k = 0; k < 3072; k += 8) {
        U8 uq; uq.u = *(const uint4*)(qr + k);
        float4 h0 = *(const float4*)(hr + k);
        float4 h1 = *(const float4*)(hr + k + 4);
        float4 b0 = *(const float4*)(bv + k);
        float4 b1 = *(const float4*)(bv + k + 4);
        acc += b2f(uq.s[0]) * h0.x * b0.x + b2f(uq.s[1]) * h0.y * b0.y +
               b2f(uq.s[2]) * h0.z * b0.z + b2f(uq.s[3]) * h0.w * b0.w +
               b2f(uq.s[4]) * h1.x * b1.x + b2f(uq.s[5]) * h1.y * b1.y +
               b2f(uq.s[6]) * h1.z * b1.z + b2f(uq.s[7]) * h1.w * b1.w;
    }
    cb[idx] = acc;
}

// ---------------- main BT-GEMM ----------------
// C(M x N) = A(M x kdim) * Bt(N x kdim)^T, 128x128 tile, BK=32, 4 waves 2x2.
// bf16 operands use global_load_lds (m97); fp32 operands use reg-prefetch + cvt.
// EPI 0: A=q fp32, B=Wq fp32.   qbuf[r*3072+c] = bf16(acc*scale + bq[c]);  z=1
// EPI 1: A=qbuf bf16 (batch b=z>>3), B=wvh bf16 (h=z&7).
//        tbuf[(z*128+r)*1024+c] = bf16(acc);  M=128 per block (y=1)
// EPI 2: A=v/vb, B=tbuf bf16 (batch z).
//        out[((z*8+h)*1024+r)*128+d] = fp32(acc*scale + cb + hbias[h])
template <int EPI, bool A_BF16, bool B_BF16>
__global__ void __launch_bounds__(256)
gemm_bt(const void* __restrict__ Ap, const void* __restrict__ Bp, void* __restrict__ C,
        const float* __restrict__ ss, int ss_idx, const float* __restrict__ g,
        const float* __restrict__ bias, const float* __restrict__ cb,
        const float* __restrict__ hbias, int kdim, size_t abatch, size_t bbatch) {
    constexpr int BK = 32;
    __shared__ __align__(16) u16 sA[128 * BK];
    __shared__ __align__(16) u16 sB[128 * BK];

    const int tid = threadIdx.x;
    const int lane = tid & 63, wv = tid >> 6;
    const int wm = (wv & 1) * 64, wn = (wv >> 1) * 64;
    const int lr = lane & 15, quad = lane >> 4;
    const int z = blockIdx.z;
    const int arow0 = blockIdx.y * 128;
    const int bcol0 = blockIdx.x * 128;

    size_t aoff, boff;
    if constexpr (EPI == 1) {
        aoff = (size_t)(z >> 3) * abatch;
        boff = (size_t)(z & 7) * bbatch;
    } else {
        aoff = (size_t)z * abatch;
        boff = (size_t)z * bbatch;
    }

    // staging map: thread t covers LDS row r0 (and r0+64), cols [c0, c0+8)
    const int r0 = tid >> 2, c0 = (tid & 3) * 8;

    // ---- operand pointers ----
    const u16* uA0 = nullptr; const float* fA0 = nullptr; const float* fA1 = nullptr;
    const u16* uB0 = nullptr; const float* fB0 = nullptr; const float* fB1 = nullptr;
    if constexpr (A_BF16) {
        uA0 = (const u16*)Ap + aoff + (size_t)(arow0 + r0) * kdim + c0;
    } else {
        fA0 = (const float*)Ap + aoff + (size_t)(arow0 + r0) * kdim + c0;
        fA1 = fA0 + (size_t)64 * kdim;
    }
    if constexpr (B_BF16) {
        uB0 = (const u16*)Bp + boff + (size_t)(bcol0 + r0) * kdim + c0;
    } else {
        fB0 = (const float*)Bp + boff + (size_t)(bcol0 + r0) * kdim + c0;
        fB1 = fB0 + (size_t)64 * kdim;
    }
    const size_t ldk64 = (size_t)64 * kdim;

    // ---- prefetch tile 0 for fp32 operands ----
    float4 a0a, a0b, a1a, a1b, b0a, b0b, b1a, b1b;
    if constexpr (!A_BF16) {
        a0a = *(const float4*)fA0; a0b = *(const float4*)(fA0 + 4);
        a1a = *(const float4*)fA1; a1b = *(const float4*)(fA1 + 4);
        fA0 += BK; fA1 += BK;
    }
    if constexpr (!B_BF16) {
        b0a = *(const float4*)fB0; b0b = *(const float4*)(fB0 + 4);
        b1a = *(const float4*)fB1; b1b = *(const float4*)(fB1 + 4);
        fB0 += BK; fB1 += BK;
    }

    f32x4 acc[4][4];
#pragma unroll
    for (int im = 0; im < 4; im++)
#pragma unroll
        for (int in = 0; in < 4; in++) acc[im][in] = (f32x4){0.f, 0.f, 0.f, 0.f};

    for (int kt = 0; kt < kdim; kt += BK) {
        __syncthreads();
        if constexpr (A_BF16) {
            gld16(uA0, sA + (size_t)tid * 8);
            gld16(uA0 + ldk64, sA + 2048 + (size_t)tid * 8);
            uA0 += BK;
        } else {
            *(uint4*)(sA + (size_t)tid * 8) = cvt8(a0a, a0b);
            *(uint4*)(sA + 2048 + (size_t)tid * 8) = cvt8(a1a, a1b);
        }
        if constexpr (B_BF16) {
            gld16(uB0, sB + (size_t)tid * 8);
            gld16(uB0 + ldk64, sB + 2048 + (size_t)tid * 8);
            uB0 += BK;
        } else {
            *(uint4*)(sB + (size_t)tid * 8) = cvt8(b0a, b0b);
            *(uint4*)(sB + 2048 + (size_t)tid * 8) = cvt8(b1a, b1b);
        }
        __syncthreads();

        // prefetch next fp32 tile (overlaps with MFMA below)
        if (kt + BK < kdim) {
            if constexpr (!A_BF16) {
                a0a = *(const float4*)fA0; a0b = *(const float4*)(fA0 + 4);
                a1a = *(const float4*)fA1; a1b = *(const float4*)(fA1 + 4);
                fA0 += BK; fA1 += BK;
            }
            if constexpr (!B_BF16) {
                b0a = *(const float4*)fB0; b0b = *(const float4*)(fB0 + 4);
                b1a = *(const float4*)fB1; b1b = *(const float4*)(fB1 + 4);
                fB0 += BK; fB1 += BK;
            }
        }

        bf16x8 af[4], bfr[4];
#pragma unroll
        for (int im = 0; im < 4; im++)
            af[im] = *(const bf16x8*)(sA + (wm + im * 16 + lr) * BK + quad * 8);
#pragma unroll
        for (int in = 0; in < 4; in++)
            bfr[in] = *(const bf16x8*)(sB + (wn + in * 16 + lr) * BK + quad * 8);
#pragma unroll
        for (int im = 0; im < 4; im++)
#pragma unroll
            for (int in = 0; in < 4; in++)
                acc[im][in] = __builtin_amdgcn_mfma_f32_16x16x32_bf16(af[im], bfr[in], acc[im][in], 0, 0, 0);
    }

    float scale = 1.f;
    if constexpr (EPI == 0 || EPI == 2) scale = g[0] / sqrtf(ss[ss_idx]);

#pragma unroll
    for (int im = 0; im < 4; im++) {
#pragma unroll
        for (int in = 0; in < 4; in++) {
#pragma unroll
            for (int reg = 0; reg < 4; reg++) {
                int gr = arow0 + wm + im * 16 + quad * 4 + reg;  // row (M)
                int gc = bcol0 + wn + in * 16 + lr;              // col (N)
                float val = acc[im][in][reg];
                if constexpr (EPI == 0) {
                    ((u16*)C)[(size_t)gr * 3072 + gc] = f2b(val * scale + bias[gc]);
                } else if constexpr (EPI == 1) {
                    ((u16*)C)[((size_t)z * 128 + gr) * 1024 + gc] = f2b(val);
                } else {
                    int h = gc >> 7, d = gc & 127;
                    float o = val * scale + cb[(size_t)z * 1024 + gc] + hbias[h];
                    ((float*)C)[(((size_t)z * 8 + h) * 1024 + gr) * 128 + d] = o;
                }
            }
        }
    }
}

// ---------------- launch ----------------

extern "C" void kernel_launch(void* const* d_in, const int* in_sizes, int n_in,
                              void* d_out, int out_size, void* d_ws, size_t ws_size,
                              hipStream_t stream) {
    (void)in_sizes; (void)n_in; (void)out_size;
    const float* v  = (const float*)d_in[0];   // (16,1024,1024) fp32
    const float* q  = (const float*)d_in[1];   // (16,128,1024)  fp32
    const float* Wv = (const float*)d_in[2];   // (3072,1024)    fp32
    const float* gv = (const float*)d_in[3];
    const float* bv = (const float*)d_in[4];   // (3072)
    const float* Wq = (const float*)d_in[5];   // (3072,1024)
    const float* gq = (const float*)d_in[6];
    const float* bq = (const float*)d_in[7];   // (3072)
    const float* hm = (const float*)d_in[8];   // (8,3072)
    const float* hb = (const float*)d_in[9];   // (8)
    float* out = (float*)d_out;                // fp32 output (16,8,1024,128) = 64 MB

    // workspace layout (floor 46.2 MB; +33.5 MB vb if available)
    char* ws = (char*)d_ws;
    float* ss   = (float*)ws;                          // 256 B
    float* cb   = (float*)(ws + 256);                  // 64 KB
    u16*   qbuf = (u16*)(ws + 256 + 65536);            // 2048*3072 bf16 = 12 MB
    u16*   tbuf = (u16*)(ws + 256 + 65536 + 12582912); // 16*1024*1024 bf16 = 33.5 MB
    u16*   vb   = (u16*)(ws + 256 + 65536 + 12582912 + 33554432);  // optional 33.5 MB
    const size_t need_vb = 256 + 65536 + 12582912 + 33554432 + 33554432;  // ~80.2 MB
    const bool fullfat = (ws_size >= need_vb);

    // wvh (8*1024*3072 bf16 = 50.3 MB) lives in d_out (64 MB), dead before gemm<2> writes out
    u16* wvh = (u16*)d_out;

    zero_ss<<<1, 64, 0, stream>>>(ss);
    sumsq_k<<<dim3(256, 2), 256, 0, stream>>>(Wv, Wq, ss, 3072 * 1024);

    // wvh[h][c][k] = bf16(hm[h,k]*Wv[k,c])
    twvh_k<<<dim3(32, 96), dim3(32, 8), 0, stream>>>(Wv, hm, wvh);

    // q_ = q * wn(Wq)^T + bq   (2048 x 3072), fp32 inputs cvt-staged
    gemm_bt<0, false, false><<<dim3(24, 16, 1), 256, 0, stream>>>(
        q, Wq, qbuf, ss, 1, gq, bq, nullptr, nullptr, 1024, 0, 0);

    // cb[b,hd] = sum_k bv*hm*q_
    const_k<<<64, 256, 0, stream>>>(qbuf, bv, hm, cb);

    // T[b,h,d,c] = sum_k q_[b,d,k] * wvh[h,c,k]   pure-bf16, gld16 staging
    gemm_bt<1, true, true><<<dim3(8, 1, 128), 256, 0, stream>>>(
        qbuf, wvh, tbuf, ss, 0, nullptr, nullptr, nullptr, nullptr,
        3072, (size_t)128 * 3072, (size_t)1024 * 3072);

    // logits[b,h,n,d] = scale_v * sum_c v[b,n,c]*T[b,hd,c] + cb[b,hd] + hbias[h]
    if (fullfat) {
        cvt_v<<<4096, 256, 0, stream>>>(v, vb, 16777216);
        gemm_bt<2, true, true><<<dim3(8, 8, 16), 256, 0, stream>>>(
            vb, tbuf, out, ss, 0, gv, nullptr, cb, hb, 1024, 1048576, 1048576);
    } else {
        gemm_bt<2, false, true><<<dim3(8, 8, 16), 256, 0, stream>>>(
            v, tbuf, out, ss, 0, gv, nullptr, cb, hb, 1024, 1048576, 1048576);
    }
}

// Round 6
// 498.829 us; speedup vs baseline: 1.0267x; 1.0097x over previous
//
#include <hip/hip_runtime.h>
#include <hip/hip_bf16.h>
#include <math.h>

typedef unsigned short u16;
typedef unsigned int u32;

typedef __bf16 bf16x8 __attribute__((ext_vector_type(8)));
typedef float f32x4 __attribute__((ext_vector_type(4)));

union U8 { uint4 u; u16 s[8]; };

__device__ __forceinline__ float b2f(u16 x) {
    u32 y = ((u32)x) << 16;
    return __builtin_bit_cast(float, y);
}
__device__ __forceinline__ u16 f2b(float f) {
    u32 x = __builtin_bit_cast(u32, f);
    u32 r = x + 0x7fffu + ((x >> 16) & 1u);
    return (u16)(r >> 16);
}
// pack 8 fp32 -> 8 bf16 (one uint4)
__device__ __forceinline__ uint4 cvt8(float4 a, float4 b) {
    U8 o;
    o.s[0] = f2b(a.x); o.s[1] = f2b(a.y); o.s[2] = f2b(a.z); o.s[3] = f2b(a.w);
    o.s[4] = f2b(b.x); o.s[5] = f2b(b.y); o.s[6] = f2b(b.z); o.s[7] = f2b(b.w);
    return o.u;
}

// ---------------- small kernels ----------------

__global__ void __launch_bounds__(64) zero_ss(float* ss) {
    if (threadIdx.x < 2) ss[threadIdx.x] = 0.f;
}

// sum of squares of Wv (y=0) / Wq (y=1), each 3072*1024 fp32
__global__ void __launch_bounds__(256) sumsq_k(const float* __restrict__ Wv,
                                               const float* __restrict__ Wq,
                                               float* __restrict__ ss, int n) {
    const float* W = (blockIdx.y == 0) ? Wv : Wq;
    float acc = 0.f;
    size_t stride = (size_t)gridDim.x * 256 * 8;
    for (size_t i = ((size_t)blockIdx.x * 256 + threadIdx.x) * 8; i < (size_t)n; i += stride) {
        float4 a = *(const float4*)(W + i);
        float4 b = *(const float4*)(W + i + 4);
        acc += a.x * a.x + a.y * a.y + a.z * a.z + a.w * a.w;
        acc += b.x * b.x + b.y * b.y + b.z * b.z + b.w * b.w;
    }
#pragma unroll
    for (int o = 32; o > 0; o >>= 1) acc += __shfl_down(acc, o, 64);
    __shared__ float red[4];
    int lane = threadIdx.x & 63, wv = threadIdx.x >> 6;
    if (lane == 0) red[wv] = acc;
    __syncthreads();
    if (threadIdx.x == 0) atomicAdd(&ss[blockIdx.y], red[0] + red[1] + red[2] + red[3]);
}

// wvh[h][c][k] = bf16(hm[h,k] * Wv[k,c])  -- fused transpose + 8-head scale
__global__ void __launch_bounds__(256) twvh_k(const float* __restrict__ Wv,
                                              const float* __restrict__ hm,
                                              u16* __restrict__ wvh) {
    __shared__ float t[32][33];
    int cx0 = blockIdx.x * 32;   // c base
    int ky0 = blockIdx.y * 32;   // k base
    int tx = threadIdx.x, ty = threadIdx.y;
#pragma unroll
    for (int j = ty; j < 32; j += 8)
        t[j][tx] = Wv[(size_t)(ky0 + j) * 1024 + cx0 + tx];
    __syncthreads();
    int k = ky0 + tx;
    float hv[8];
#pragma unroll
    for (int h = 0; h < 8; h++) hv[h] = hm[(size_t)h * 3072 + k];
#pragma unroll
    for (int j = ty; j < 32; j += 8) {
        float w = t[tx][j];           // Wv[k][cx0+j]
        int c = cx0 + j;
#pragma unroll
        for (int h = 0; h < 8; h++)
            wvh[(size_t)h * 3145728 + (size_t)c * 3072 + k] = f2b(hv[h] * w);
    }
}

// vb[i] = bf16(v[i]), n elements
__global__ void __launch_bounds__(256) cvt_v(const float* __restrict__ v,
                                             u16* __restrict__ vb, int n) {
    size_t stride = (size_t)gridDim.x * 256 * 8;
    for (size_t i = ((size_t)blockIdx.x * 256 + threadIdx.x) * 8; i < (size_t)n; i += stride) {
        float4 a = *(const float4*)(v + i);
        float4 b = *(const float4*)(v + i + 4);
        *(uint4*)(vb + i) = cvt8(a, b);
    }
}

// cb[b*1024 + h*128 + d] = sum_k bv[k]*hm[h,k]*q_[b*128+d, k]   (fp32 acc)
__global__ void __launch_bounds__(256) const_k(const u16* __restrict__ qbuf,
                                               const float* __restrict__ bv,
                                               const float* __restrict__ hm,
                                               float* __restrict__ cb) {
    int idx = blockIdx.x * 256 + threadIdx.x;  // 0..16383
    int b = idx >> 10, hd = idx & 1023, h = hd >> 7, d = hd & 127;
    const u16* qr = qbuf + ((size_t)b * 128 + d) * 3072;
    const float* hr = hm + (size_t)h * 3072;
    float acc = 0.f;
    for (int k = 0; k < 3072; k += 8) {
        U8 uq; uq.u = *(const uint4*)(qr + k);
        float4 h0 = *(const float4*)(hr + k);
        float4 h1 = *(const float4*)(hr + k + 4);
        float4 b0 = *(const float4*)(bv + k);
        float4 b1 = *(const float4*)(bv + k + 4);
        acc += b2f(uq.s[0]) * h0.x * b0.x + b2f(uq.s[1]) * h0.y * b0.y +
               b2f(uq.s[2]) * h0.z * b0.z + b2f(uq.s[3]) * h0.w * b0.w +
               b2f(uq.s[4]) * h1.x * b1.x + b2f(uq.s[5]) * h1.y * b1.y +
               b2f(uq.s[6]) * h1.z * b1.z + b2f(uq.s[7]) * h1.w * b1.w;
    }
    cb[idx] = acc;
}

// ---------------- main BT-GEMM (swizzled LDS + single-barrier ping-pong) ----------------
// C(M x N) = A(M x kdim) * Bt(N x kdim)^T, 128x128 tile, BK=32, 4 waves 2x2.
// LDS layout swizzle: element-group (row, qc) at u16 offset row*32 + ((qc ^ ((row>>1)&3))*8)
//   -> frag ds_read_b128 is <=2-way bank-aliased (free) instead of 4-way.
// One __syncthreads per K-iter; 2 LDS buffers; global prefetch in regs.
// EPI 0: A=q fp32, B=Wq fp32.   qbuf[r*3072+c] = bf16(acc*scale + bq[c])
// EPI 1: A=qbuf bf16 (b=z>>3), B=wvh bf16 (h=z&7). tbuf[(z*128+r)*1024+c]=bf16(acc)
// EPI 2: A=v/vb, B=tbuf bf16 (batch z). out[((z*8+h)*1024+r)*128+d]=fp32(...)
template <int EPI, bool A_BF16, bool B_BF16>
__global__ void __launch_bounds__(256)
gemm_bt(const void* __restrict__ Ap, const void* __restrict__ Bp, void* __restrict__ C,
        const float* __restrict__ ss, int ss_idx, const float* __restrict__ g,
        const float* __restrict__ bias, const float* __restrict__ cb,
        const float* __restrict__ hbias, int kdim, size_t abatch, size_t bbatch) {
    constexpr int BK = 32;
    __shared__ __align__(16) u16 sA[2][128 * BK];
    __shared__ __align__(16) u16 sB[2][128 * BK];

    const int tid = threadIdx.x;
    const int lane = tid & 63, wv = tid >> 6;
    const int wm = (wv & 1) * 64, wn = (wv >> 1) * 64;
    const int lr = lane & 15, quad = lane >> 4;
    const int z = blockIdx.z;
    const int arow0 = blockIdx.y * 128;
    const int bcol0 = blockIdx.x * 128;

    size_t aoff, boff;
    if constexpr (EPI == 1) {
        aoff = (size_t)(z >> 3) * abatch;
        boff = (size_t)(z & 7) * bbatch;
    } else {
        aoff = (size_t)z * abatch;
        boff = (size_t)z * bbatch;
    }

    // staging map: thread t covers rows t>>2 and (t>>2)+64, col-group t&3 (8 elems)
    const int r0 = tid >> 2, c0 = (tid & 3) * 8;
    // swizzled write offsets (u16): row*32 + ((qc ^ ((row>>1)&3))*8); (row>>1)&3 == (tid>>3)&3
    const int w0 = r0 * 32 + (((tid & 3) ^ ((tid >> 3) & 3)) * 8);
    const int w1 = w0 + 64 * 32;
    // swizzled read col-offset: ((quad ^ ((lr>>1)&3)) * 8)
    const int rsw = ((quad ^ ((lr >> 1) & 3)) * 8);

    // ---- operand pointers ----
    const u16* uA0 = nullptr; const float* fA0 = nullptr; const float* fA1 = nullptr;
    const u16* uB0 = nullptr; const float* fB0 = nullptr; const float* fB1 = nullptr;
    if constexpr (A_BF16) {
        uA0 = (const u16*)Ap + aoff + (size_t)(arow0 + r0) * kdim + c0;
    } else {
        fA0 = (const float*)Ap + aoff + (size_t)(arow0 + r0) * kdim + c0;
        fA1 = fA0 + (size_t)64 * kdim;
    }
    if constexpr (B_BF16) {
        uB0 = (const u16*)Bp + boff + (size_t)(bcol0 + r0) * kdim + c0;
    } else {
        fB0 = (const float*)Bp + boff + (size_t)(bcol0 + r0) * kdim + c0;
        fB1 = fB0 + (size_t)64 * kdim;
    }
    const size_t ldk64 = (size_t)64 * kdim;

    // ---- prologue: load tile 0 and store into buffer 0 ----
    {
        uint4 pa0, pa1, pb0, pb1;
        if constexpr (A_BF16) {
            pa0 = *(const uint4*)uA0; pa1 = *(const uint4*)(uA0 + ldk64); uA0 += BK;
        } else {
            float4 x0 = *(const float4*)fA0, x1 = *(const float4*)(fA0 + 4);
            float4 y0 = *(const float4*)fA1, y1 = *(const float4*)(fA1 + 4);
            pa0 = cvt8(x0, x1); pa1 = cvt8(y0, y1); fA0 += BK; fA1 += BK;
        }
        if constexpr (B_BF16) {
            pb0 = *(const uint4*)uB0; pb1 = *(const uint4*)(uB0 + ldk64); uB0 += BK;
        } else {
            float4 x0 = *(const float4*)fB0, x1 = *(const float4*)(fB0 + 4);
            float4 y0 = *(const float4*)fB1, y1 = *(const float4*)(fB1 + 4);
            pb0 = cvt8(x0, x1); pb1 = cvt8(y0, y1); fB0 += BK; fB1 += BK;
        }
        *(uint4*)(sA[0] + w0) = pa0; *(uint4*)(sA[0] + w1) = pa1;
        *(uint4*)(sB[0] + w0) = pb0; *(uint4*)(sB[0] + w1) = pb1;
    }

    f32x4 acc[4][4];
#pragma unroll
    for (int im = 0; im < 4; im++)
#pragma unroll
        for (int in = 0; in < 4; in++) acc[im][in] = (f32x4){0.f, 0.f, 0.f, 0.f};

    int p = 0;
    for (int kt = 0; kt < kdim; kt += BK) {
        __syncthreads();
        const bool more = (kt + BK < kdim);

        // issue next-tile global loads early (consumed after MFMA)
        uint4 na0, na1, nb0, nb1;
        float4 ax0, ax1, ay0, ay1, bx0, bx1, by0, by1;
        if (more) {
            if constexpr (A_BF16) {
                na0 = *(const uint4*)uA0; na1 = *(const uint4*)(uA0 + ldk64); uA0 += BK;
            } else {
                ax0 = *(const float4*)fA0; ax1 = *(const float4*)(fA0 + 4);
                ay0 = *(const float4*)fA1; ay1 = *(const float4*)(fA1 + 4);
                fA0 += BK; fA1 += BK;
            }
            if constexpr (B_BF16) {
                nb0 = *(const uint4*)uB0; nb1 = *(const uint4*)(uB0 + ldk64); uB0 += BK;
            } else {
                bx0 = *(const float4*)fB0; bx1 = *(const float4*)(fB0 + 4);
                by0 = *(const float4*)fB1; by1 = *(const float4*)(fB1 + 4);
                fB0 += BK; fB1 += BK;
            }
        }

        const u16* sAp = sA[p];
        const u16* sBp = sB[p];
        bf16x8 af[4], bfr[4];
#pragma unroll
        for (int im = 0; im < 4; im++)
            af[im] = *(const bf16x8*)(sAp + (wm + im * 16 + lr) * 32 + rsw);
#pragma unroll
        for (int in = 0; in < 4; in++)
            bfr[in] = *(const bf16x8*)(sBp + (wn + in * 16 + lr) * 32 + rsw);
#pragma unroll
        for (int im = 0; im < 4; im++)
#pragma unroll
            for (int in = 0; in < 4; in++)
                acc[im][in] = __builtin_amdgcn_mfma_f32_16x16x32_bf16(af[im], bfr[in], acc[im][in], 0, 0, 0);

        if (more) {
            u16* dA = sA[p ^ 1];
            u16* dB = sB[p ^ 1];
            if constexpr (A_BF16) {
                *(uint4*)(dA + w0) = na0; *(uint4*)(dA + w1) = na1;
            } else {
                *(uint4*)(dA + w0) = cvt8(ax0, ax1); *(uint4*)(dA + w1) = cvt8(ay0, ay1);
            }
            if constexpr (B_BF16) {
                *(uint4*)(dB + w0) = nb0; *(uint4*)(dB + w1) = nb1;
            } else {
                *(uint4*)(dB + w0) = cvt8(bx0, bx1); *(uint4*)(dB + w1) = cvt8(by0, by1);
            }
        }
        p ^= 1;
    }

    float scale = 1.f;
    if constexpr (EPI == 0 || EPI == 2) scale = g[0] / sqrtf(ss[ss_idx]);

#pragma unroll
    for (int im = 0; im < 4; im++) {
#pragma unroll
        for (int in = 0; in < 4; in++) {
#pragma unroll
            for (int reg = 0; reg < 4; reg++) {
                int gr = arow0 + wm + im * 16 + quad * 4 + reg;  // row (M)
                int gc = bcol0 + wn + in * 16 + lr;              // col (N)
                float val = acc[im][in][reg];
                if constexpr (EPI == 0) {
                    ((u16*)C)[(size_t)gr * 3072 + gc] = f2b(val * scale + bias[gc]);
                } else if constexpr (EPI == 1) {
                    ((u16*)C)[((size_t)z * 128 + gr) * 1024 + gc] = f2b(val);
                } else {
                    int h = gc >> 7, d = gc & 127;
                    float o = val * scale + cb[(size_t)z * 1024 + gc] + hbias[h];
                    ((float*)C)[(((size_t)z * 8 + h) * 1024 + gr) * 128 + d] = o;
                }
            }
        }
    }
}

// ---------------- launch ----------------

extern "C" void kernel_launch(void* const* d_in, const int* in_sizes, int n_in,
                              void* d_out, int out_size, void* d_ws, size_t ws_size,
                              hipStream_t stream) {
    (void)in_sizes; (void)n_in; (void)out_size;
    const float* v  = (const float*)d_in[0];   // (16,1024,1024) fp32
    const float* q  = (const float*)d_in[1];   // (16,128,1024)  fp32
    const float* Wv = (const float*)d_in[2];   // (3072,1024)    fp32
    const float* gv = (const float*)d_in[3];
    const float* bv = (const float*)d_in[4];   // (3072)
    const float* Wq = (const float*)d_in[5];   // (3072,1024)
    const float* gq = (const float*)d_in[6];
    const float* bq = (const float*)d_in[7];   // (3072)
    const float* hm = (const float*)d_in[8];   // (8,3072)
    const float* hb = (const float*)d_in[9];   // (8)
    float* out = (float*)d_out;                // fp32 output (16,8,1024,128) = 64 MB

    // workspace layout (floor 46.2 MB; +33.5 MB vb if available)
    char* ws = (char*)d_ws;
    float* ss   = (float*)ws;                          // 256 B
    float* cb   = (float*)(ws + 256);                  // 64 KB
    u16*   qbuf = (u16*)(ws + 256 + 65536);            // 2048*3072 bf16 = 12 MB
    u16*   tbuf = (u16*)(ws + 256 + 65536 + 12582912); // 16*1024*1024 bf16 = 33.5 MB
    u16*   vb   = (u16*)(ws + 256 + 65536 + 12582912 + 33554432);  // optional 33.5 MB
    const size_t need_vb = 256 + 65536 + 12582912 + 33554432 + 33554432;  // ~80.2 MB
    const bool fullfat = (ws_size >= need_vb);

    // wvh (8*1024*3072 bf16 = 50.3 MB) lives in d_out (64 MB), dead before gemm<2> writes out
    u16* wvh = (u16*)d_out;

    zero_ss<<<1, 64, 0, stream>>>(ss);
    sumsq_k<<<dim3(256, 2), 256, 0, stream>>>(Wv, Wq, ss, 3072 * 1024);

    // wvh[h][c][k] = bf16(hm[h,k]*Wv[k,c])
    twvh_k<<<dim3(32, 96), dim3(32, 8), 0, stream>>>(Wv, hm, wvh);

    // q_ = q * wn(Wq)^T + bq   (2048 x 3072), fp32 inputs cvt-staged
    gemm_bt<0, false, false><<<dim3(24, 16, 1), 256, 0, stream>>>(
        q, Wq, qbuf, ss, 1, gq, bq, nullptr, nullptr, 1024, 0, 0);

    // cb[b,hd] = sum_k bv*hm*q_
    const_k<<<64, 256, 0, stream>>>(qbuf, bv, hm, cb);

    // T[b,h,d,c] = sum_k q_[b,d,k] * wvh[h,c,k]   pure-bf16
    gemm_bt<1, true, true><<<dim3(8, 1, 128), 256, 0, stream>>>(
        qbuf, wvh, tbuf, ss, 0, nullptr, nullptr, nullptr, nullptr,
        3072, (size_t)128 * 3072, (size_t)1024 * 3072);

    // logits[b,h,n,d] = scale_v * sum_c v[b,n,c]*T[b,hd,c] + cb[b,hd] + hbias[h]
    if (fullfat) {
        cvt_v<<<4096, 256, 0, stream>>>(v, vb, 16777216);
        gemm_bt<2, true, true><<<dim3(8, 8, 16), 256, 0, stream>>>(
            vb, tbuf, out, ss, 0, gv, nullptr, cb, hb, 1024, 1048576, 1048576);
    } else {
        gemm_bt<2, false, true><<<dim3(8, 8, 16), 256, 0, stream>>>(
            v, tbuf, out, ss, 0, gv, nullptr, cb, hb, 1024, 1048576, 1048576);
    }
}